// Round 2
// baseline (486.764 us; speedup 1.0000x reference)
//
#include <hip/hip_runtime.h>

// Problem constants (fixed by reference setup_inputs)
#define BB   8
#define CCH  128
#define CR   32
#define HH   256
#define WW   256
#define NHH  128
#define NWW  128

#define WPB  16          // windows per block (along nW)
#define TPB  128         // threads per block
#define TS   65          // tile row stride (odd -> conflict-free lanes-over-c)
#define QMS  20          // qmean row stride (multiple of 4 -> aligned float4 reads)
#define GS   17          // g row stride (odd)

// Kernel 0: M[c'][c] = (1/sqrt(Cr)) * sum_r Wq[c'][r] * Wk[c][r]
__global__ void compute_m_kernel(const float* __restrict__ Wq,
                                 const float* __restrict__ Wk,
                                 float* __restrict__ M) {
    int idx = blockIdx.x * blockDim.x + threadIdx.x;   // 0..16383
    int cp = idx >> 7;     // c' (row of M)
    int c  = idx & 127;    // c  (col of M)
    float s = 0.f;
#pragma unroll
    for (int r = 0; r < CR; ++r)
        s += Wq[cp * CR + r] * Wk[c * CR + r];
    M[idx] = s * 0.17677669529663687f;   // 32^-0.5
}

__global__ __launch_bounds__(TPB)
void attn_downsample_kernel(const float* __restrict__ fm,
                            const float* __restrict__ M,
                            float* __restrict__ out) {
    __shared__ float tile[CCH][TS];     // [c][rj], rj = r*32 + j, j=0..31 (32 input cols)
    __shared__ float qm[CCH][QMS];      // [c'][jw], jw=0..15
    __shared__ float gl[CCH][GS];       // [c][jw]
    __shared__ float attn_t[4][WPB];    // [token][jw]

    const int wseg = blockIdx.x;        // 0..7
    const int nh   = blockIdx.y;        // 0..127
    const int b    = blockIdx.z;        // 0..7
    const int t    = threadIdx.x;       // 0..127

    const int w0   = wseg * (WPB * 2);  // input column base (32 cols)
    const int row0 = nh * 2;            // input row base (2 rows)

    // ---------------- Phase A: stage tile (128 c x 64 rj floats) ----------------
    // 8192 floats, 128 threads * float4 = 512 per iter -> 16 iters.
#pragma unroll 4
    for (int k = 0; k < 16; ++k) {
        int q  = k * TPB + t;        // float4 index 0..2047
        int c  = q >> 4;             // 16 float4 per c-row
        int rj = (q & 15) << 2;      // 0..60
        int r  = rj >> 5;
        int j  = rj & 31;
        const float4 v = *reinterpret_cast<const float4*>(
            fm + (((b * CCH + c) * HH + row0 + r) * WW + w0 + j));
        tile[c][rj + 0] = v.x;
        tile[c][rj + 1] = v.y;
        tile[c][rj + 2] = v.z;
        tile[c][rj + 3] = v.w;
    }
    __syncthreads();

    // ---------------- Phase B: qmean[c][jw] = 0.25 * sum of 4 window pixels ----
    {
        int jw = t & 15;
        int cg = t >> 4;             // 0..7
#pragma unroll 4
        for (int i = 0; i < 16; ++i) {
            int c = cg * 16 + i;
            float s = tile[c][2 * jw] + tile[c][2 * jw + 1]
                    + tile[c][32 + 2 * jw] + tile[c][32 + 2 * jw + 1];
            qm[c][jw] = 0.25f * s;
        }
    }
    __syncthreads();

    // ---------------- Phase C: g[c][jw] = sum_c' qm[c'][jw] * M[c'][c] ---------
    {
        int c = t;                   // 0..127
        float g[16];
#pragma unroll
        for (int k = 0; k < 16; ++k) g[k] = 0.f;

#pragma unroll 4
        for (int cp = 0; cp < 128; ++cp) {
            float m = M[cp * 128 + c];               // coalesced, L2-hot
            const float4 a0 = *reinterpret_cast<const float4*>(&qm[cp][0]);
            const float4 a1 = *reinterpret_cast<const float4*>(&qm[cp][4]);
            const float4 a2 = *reinterpret_cast<const float4*>(&qm[cp][8]);
            const float4 a3 = *reinterpret_cast<const float4*>(&qm[cp][12]);
            g[0]  += a0.x * m;  g[1]  += a0.y * m;  g[2]  += a0.z * m;  g[3]  += a0.w * m;
            g[4]  += a1.x * m;  g[5]  += a1.y * m;  g[6]  += a1.z * m;  g[7]  += a1.w * m;
            g[8]  += a2.x * m;  g[9]  += a2.y * m;  g[10] += a2.z * m;  g[11] += a2.w * m;
            g[12] += a3.x * m;  g[13] += a3.y * m;  g[14] += a3.z * m;  g[15] += a3.w * m;
        }
#pragma unroll
        for (int k = 0; k < 16; ++k) gl[c][k] = g[k];
    }
    __syncthreads();

    // ---------------- Phase D: qk + softmax -> attn_t ---------------------------
    {
        int jw   = t >> 3;           // 0..15
        int tsub = t & 7;            // 0..7, owns c = tsub*16 .. +15
        float qk0 = 0.f, qk1 = 0.f, qk2 = 0.f, qk3 = 0.f;
#pragma unroll 4
        for (int i = 0; i < 16; ++i) {
            int c = tsub * 16 + i;
            float g  = gl[c][jw];
            qk0 += g * tile[c][2 * jw];
            qk1 += g * tile[c][2 * jw + 1];
            qk2 += g * tile[c][32 + 2 * jw];
            qk3 += g * tile[c][32 + 2 * jw + 1];
        }
#pragma unroll
        for (int off = 1; off < 8; off <<= 1) {
            qk0 += __shfl_xor(qk0, off);
            qk1 += __shfl_xor(qk1, off);
            qk2 += __shfl_xor(qk2, off);
            qk3 += __shfl_xor(qk3, off);
        }
        float mx = fmaxf(fmaxf(qk0, qk1), fmaxf(qk2, qk3));
        float e0 = expf(qk0 - mx);
        float e1 = expf(qk1 - mx);
        float e2 = expf(qk2 - mx);
        float e3 = expf(qk3 - mx);
        float inv = 1.0f / (e0 + e1 + e2 + e3);
        if (tsub == 0) {
            attn_t[0][jw] = e0 * inv;
            attn_t[1][jw] = e1 * inv;
            attn_t[2][jw] = e2 * inv;
            attn_t[3][jw] = e3 * inv;
        }
    }
    __syncthreads();

    // ---------------- Phase E: out[jw][c] = sum_t attn[t] * x[t][c] ------------
    {
        int jw = t & 15;
        int cg = t >> 4;             // 0..7
        float a0 = attn_t[0][jw];
        float a1 = attn_t[1][jw];
        float a2 = attn_t[2][jw];
        float a3 = attn_t[3][jw];
        int ow = wseg * WPB + jw;    // output column
#pragma unroll 4
        for (int i = 0; i < 16; ++i) {
            int c = cg * 16 + i;
            float o = a0 * tile[c][2 * jw]
                    + a1 * tile[c][2 * jw + 1]
                    + a2 * tile[c][32 + 2 * jw]
                    + a3 * tile[c][32 + 2 * jw + 1];
            out[((b * CCH + c) * NHH + nh) * NWW + ow] = o;
        }
    }
}

extern "C" void kernel_launch(void* const* d_in, const int* in_sizes, int n_in,
                              void* d_out, int out_size, void* d_ws, size_t ws_size,
                              hipStream_t stream) {
    const float* fm = (const float*)d_in[0];
    const float* Wq = (const float*)d_in[1];
    const float* Wk = (const float*)d_in[2];
    float* outp = (float*)d_out;
    float* Mws  = (float*)d_ws;      // 128*128 floats = 64 KB

    // Kernel 0: precompute M = Wq @ Wk^T * Cr^-0.5  (ws is re-poisoned every
    // call, so this runs every launch — same work every call, capture-safe).
    compute_m_kernel<<<dim3(64), dim3(256), 0, stream>>>(Wq, Wk, Mws);

    // Main fused kernel (infra retry — identical to round 1 design; no
    // measurements exist yet to justify a change).
    dim3 grid(NWW / WPB, NHH, BB);   // (8, 128, 8)
    attn_downsample_kernel<<<grid, dim3(TPB), 0, stream>>>(fm, Mws, outp);
}